// Round 3
// baseline (111.154 us; speedup 1.0000x reference)
//
#include <hip/hip_runtime.h>

#define S_DIM 16
#define T_DIM 12
#define BLOCK 256
#define YROW  17   // 16 species + constant-1.0 slot; gcd(17,32)=1 -> 2-way aliasing only (free)
#define RROW  13   // 12 rates + pad; gcd(13,32)=1 -> 2-way aliasing only (free)

__global__ __launch_bounds__(BLOCK) void mech_kernel(
    const float* __restrict__ y,        // (B,16) f32
    const float* __restrict__ fr,       // (B,12) f32
    const float* __restrict__ rr,       // (B,12) f32
    const float* __restrict__ stoich,   // (12,16) f32, entries in {-1,0,1}
    const float* __restrict__ effects,  // (12,16) f32
    const int* __restrict__ from_idx,
    const int* __restrict__ from_valid,
    const int* __restrict__ to_idx,
    const int* __restrict__ to_valid,
    const int* __restrict__ reversible,
    float* __restrict__ out,            // (B,16) f32
    int nb)
{
    __shared__ float s_y [BLOCK * YROW];   // 17408 B
    __shared__ float s_fr[BLOCK * RROW];   // 13312 B
    __shared__ float s_rr[BLOCK * RROW];   // 13312 B
    __shared__ float s_eff[T_DIM][S_DIM];
    __shared__ int   s_si[T_DIM], s_fi[T_DIM], s_pi[T_DIM], s_ti[T_DIM];
    __shared__ float s_rg[T_DIM];

    const int tid = threadIdx.x;
    const size_t row0 = (size_t)blockIdx.x * BLOCK;   // first batch row of this block

    // ---- mechanism decode (first 12 threads) ----
    if (tid < T_DIM) {
        int sub = 16, prod = 16;          // 16 -> constant-1.0 slot
        #pragma unroll
        for (int s = 0; s < S_DIM; ++s) {
            float v = stoich[tid * S_DIM + s];
            s_eff[tid][s] = effects[tid * S_DIM + s];
            if (v < -0.5f) sub = s;       // exactly one -1 per row
            if (v >  0.5f) prod = s;      // at most one +1 per row
        }
        s_si[tid] = sub;
        s_pi[tid] = prod;
        s_fi[tid] = from_valid[tid] ? from_idx[tid] : 16;
        s_ti[tid] = to_valid[tid]   ? to_idx[tid]   : 16;
        s_rg[tid] = reversible[tid] ? 1.0f : 0.0f;
    }

    // ---- coalesced load phase: lane-contiguous float4 (16B/lane) ----
    // y: 256 rows * 16 f32 = 1024 float4 per block
    {
        const float4* gy = (const float4*)y;          // global float4 index space
        const size_t base = row0 * 4;                 // 4 float4 per row
        const size_t limit = (size_t)nb * 4;
        #pragma unroll
        for (int k = 0; k < 4; ++k) {
            int j = tid + k * BLOCK;
            size_t jg = base + j;
            float4 v = (jg < limit) ? gy[jg] : make_float4(0.f, 0.f, 0.f, 0.f);
            int row = j >> 2, col = (j & 3) << 2;
            float* p = &s_y[row * YROW + col];
            p[0] = v.x; p[1] = v.y; p[2] = v.z; p[3] = v.w;
        }
        s_y[tid * YROW + 16] = 1.0f;
    }
    // fr/rr: 256 rows * 12 f32 = 768 float4 per block (3 float4 per row)
    {
        const float4* gf = (const float4*)fr;
        const float4* gr = (const float4*)rr;
        const size_t base = row0 * 3;
        const size_t limit = (size_t)nb * 3;
        #pragma unroll
        for (int k = 0; k < 3; ++k) {
            int j = tid + k * BLOCK;
            size_t jg = base + j;
            float4 a = make_float4(0.f, 0.f, 0.f, 0.f), c = a;
            if (jg < limit) { a = gf[jg]; c = gr[jg]; }
            int row = j / 3, part = j - row * 3;      // compiler magic-mul
            float* pf = &s_fr[row * RROW + part * 4];
            pf[0] = a.x; pf[1] = a.y; pf[2] = a.z; pf[3] = a.w;
            float* pr = &s_rr[row * RROW + part * 4];
            pr[0] = c.x; pr[1] = c.y; pr[2] = c.z; pr[3] = c.w;
        }
    }
    __syncthreads();

    // ---- compute phase: per-thread row, runtime-uniform gathers via LDS ----
    float* myY = &s_y[tid * YROW];
    const float* myF = &s_fr[tid * RROW];
    const float* myR = &s_rr[tid * RROW];

    float acc[S_DIM];
    #pragma unroll
    for (int s = 0; s < S_DIM; ++s) acc[s] = 0.0f;

    #pragma unroll
    for (int t = 0; t < T_DIM; ++t) {
        float vf = myF[t] * myY[s_fi[t]] * myY[s_si[t]];
        float vr = s_rg[t] * myR[t] * myY[s_ti[t]] * myY[s_pi[t]];
        float v  = vf - vr;
        #pragma unroll
        for (int s = 0; s < S_DIM; ++s)
            acc[s] = fmaf(v, s_eff[t][s], acc[s]);
    }

    // stage result into own LDS row (only this thread read it; no sync needed)
    #pragma unroll
    for (int s = 0; s < S_DIM; ++s) myY[s] = acc[s];
    __syncthreads();

    // ---- coalesced store phase: lane-contiguous float4 ----
    {
        float4* go = (float4*)out;
        const size_t base = row0 * 4;
        const size_t limit = (size_t)nb * 4;
        #pragma unroll
        for (int k = 0; k < 4; ++k) {
            int j = tid + k * BLOCK;
            size_t jg = base + j;
            if (jg < limit) {
                int row = j >> 2, col = (j & 3) << 2;
                const float* p = &s_y[row * YROW + col];
                go[jg] = make_float4(p[0], p[1], p[2], p[3]);
            }
        }
    }
}

extern "C" void kernel_launch(void* const* d_in, const int* in_sizes, int n_in,
                              void* d_out, int out_size, void* d_ws, size_t ws_size,
                              hipStream_t stream) {
    // setup_inputs order:
    // 0: t (f32 scalar, unused)
    // 1: y (B,16) f32        2: forward_rates (B,12) f32   3: reverse_rates (B,12) f32
    // 4: stoich (12,16) f32  5: effects (12,16) f32
    // 6: from_idx int32      7: from_valid int32(bool)
    // 8: to_idx int32        9: to_valid int32(bool)       10: reversible int32(bool)
    const float* y  = (const float*)d_in[1];
    const float* fr = (const float*)d_in[2];
    const float* rr = (const float*)d_in[3];
    const float* st = (const float*)d_in[4];
    const float* ef = (const float*)d_in[5];
    const int* fi = (const int*)d_in[6];
    const int* fv = (const int*)d_in[7];
    const int* ti = (const int*)d_in[8];
    const int* tv = (const int*)d_in[9];
    const int* rv = (const int*)d_in[10];
    float* o = (float*)d_out;

    int nb = in_sizes[1] / S_DIM;   // batch count
    int grid = (nb + BLOCK - 1) / BLOCK;
    mech_kernel<<<grid, BLOCK, 0, stream>>>(y, fr, rr, st, ef, fi, fv, ti, tv, rv, o, nb);
}